// Round 7
// baseline (192.274 us; speedup 1.0000x reference)
//
#include <hip/hip_runtime.h>
#include <hip/hip_fp8.h>
#include <hip/hip_cooperative_groups.h>

namespace cg = cooperative_groups;

#define N2    16384
#define NHALF 8192
#define KB    128      // bytes per row in fp8
#define BROW  256      // rows per block (4 row-groups x 64)
#define BCOL  256      // B-tile cols per iteration (256*128B = 32 KB/tile)
#define NQUARTER 4096  // cols per block (grid = 64 row-tiles x 4 col-quarters)
#define NITER (NQUARTER / BCOL)   // 16

using f32x4 = __attribute__((ext_vector_type(4))) float;

// exp(2*dot) == exp2(dot * 2*log2(e)); fold sqrt(2*log2(e)) into z before fp8
// quantization so the MFMA result is already in exp2 domain.
#define PRESCALE 1.6986436005760381f   // sqrt(2*log2(e))

#if __has_builtin(__builtin_amdgcn_exp2f)
#define EXP2F(x) __builtin_amdgcn_exp2f(x)
#else
#define EXP2F(x) exp2f(x)
#endif
#if __has_builtin(__builtin_amdgcn_logf)
#define LOG2F(x) __builtin_amdgcn_logf(x)
#else
#define LOG2F(x) log2f(x)
#endif

typedef const __attribute__((address_space(1))) void* gas_ptr;
typedef __attribute__((address_space(3))) void* las_ptr;

// ---------------- phase A: f32 -> fp8 e4m3 (prescaled) + zero out ----------
__device__ __forceinline__ void phaseA(const float* __restrict__ z,
                                       unsigned char* __restrict__ zq,
                                       float* __restrict__ out, int bid, int t) {
  int g = bid * 1024 + t;               // 262144 threads x 8 elems
  const float4* zin = (const float4*)z;
  float4 v0 = zin[2 * g], v1 = zin[2 * g + 1];
#if __has_builtin(__builtin_amdgcn_cvt_pk_fp8_f32)
  int lo = __builtin_amdgcn_cvt_pk_fp8_f32(v0.x * PRESCALE, v0.y * PRESCALE, 0, 0);
  lo     = __builtin_amdgcn_cvt_pk_fp8_f32(v0.z * PRESCALE, v0.w * PRESCALE, lo, 1);
  int hi = __builtin_amdgcn_cvt_pk_fp8_f32(v1.x * PRESCALE, v1.y * PRESCALE, 0, 0);
  hi     = __builtin_amdgcn_cvt_pk_fp8_f32(v1.z * PRESCALE, v1.w * PRESCALE, hi, 1);
  ((int2*)zq)[g] = make_int2(lo, hi);
#else
  float f[8] = {v0.x, v0.y, v0.z, v0.w, v1.x, v1.y, v1.z, v1.w};
  unsigned long long pk = 0;
  for (int u = 0; u < 8; ++u) {
    __hip_fp8_e4m3 qv(f[u] * PRESCALE);
    pk |= ((unsigned long long)qv.__x) << (8 * u);
  }
  ((unsigned long long*)zq)[g] = pk;
#endif
  if (g == 0) out[0] = 0.f;
}

// ---------------- phase B: fused GEMM + exp2 + per-(row,quarter) sums ------
// bid decodes as (bt = bid>>2) x (quarter = bid&3); 16 waves = 4 row-groups x
// 4 col-strips(64). A fragments (fp8: 2 VGPRs per 16x16x32 operand -> 32
// VGPRs total) register-resident. B: double-buffered 32 KB LDS tiles via
// global_load_lds DMA; XOR granule swizzle (row,k8)->(row,k8^(row&7)) applied
// on source addresses (DMA LDS dest is lane-linear). Read-side b64 access:
// each bank serves exactly 4 dwords = the wave64-b64 floor.
__device__ __forceinline__ void phaseB(const unsigned char* __restrict__ zq,
                                       float* __restrict__ Spart,
                                       int bid, int t, unsigned char* BsRaw) {
  unsigned char (*Bs)[BCOL * KB] = (unsigned char (*)[BCOL * KB])BsRaw;
  const int w = t >> 6, l = t & 63, q = l >> 4, c15 = l & 15;
  const int bt = bid >> 2, quarter = bid & 3;
  const int mg = w >> 2, ns = w & 3;
  const int rbase = bt * BROW + mg * 64;

  int srcoff[2];
#pragma unroll
  for (int j = 0; j < 2; ++j) {
    int p   = j * 1024 + t;      // physical granule id in tile (2048 x 16 B)
    int row = p >> 3;
    int pg  = p & 7;
    int k8  = pg ^ (row & 7);
    srcoff[j] = row * KB + k8 * 16;
  }

  const unsigned char* tile0 = zq + (size_t)(quarter * NQUARTER) * KB;
#pragma unroll
  for (int j = 0; j < 2; ++j)
    __builtin_amdgcn_global_load_lds((gas_ptr)(tile0 + srcoff[j]),
                                     (las_ptr)(&Bs[0][j * 16384 + w * 1024]), 16, 0, 0);

  // A fragments, fp8 16x16x32: lane holds A[m=lane&15][k=q*8+j] (8 bytes)
  long afr[4][4];
#pragma unroll
  for (int m = 0; m < 4; ++m) {
    const unsigned char* ap = zq + (size_t)(rbase + m * 16 + c15) * KB + q * 8;
#pragma unroll
    for (int s = 0; s < 4; ++s)
      afr[m][s] = *reinterpret_cast<const long*>(ap + s * 32);
  }

  float rowsum[4][4];
#pragma unroll
  for (int m = 0; m < 4; ++m)
#pragma unroll
    for (int r = 0; r < 4; ++r) rowsum[m][r] = 0.f;

  for (int it = 0; it < NITER; ++it) {
    const int buf = it & 1;
    const int C0  = quarter * NQUARTER + it * BCOL;
    __syncthreads();   // drains this wave's DMA (vmcnt) for tile it

    if (it + 1 < NITER) {
      const unsigned char* src = tile0 + (size_t)(it + 1) * BCOL * KB;
#pragma unroll
      for (int j = 0; j < 2; ++j)
        __builtin_amdgcn_global_load_lds((gas_ptr)(src + srcoff[j]),
                                         (las_ptr)(&Bs[buf ^ 1][j * 16384 + w * 1024]), 16, 0, 0);
    }

#pragma unroll
    for (int nt = 0; nt < 4; ++nt) {
      const int rloc = ns * 64 + nt * 16 + c15;   // B row within tile
      f32x4 acc[4];
#pragma unroll
      for (int m = 0; m < 4; ++m) acc[m] = (f32x4){0.f, 0.f, 0.f, 0.f};
#pragma unroll
      for (int s = 0; s < 4; ++s) {
        int pg = (2 * s + (q >> 1)) ^ (rloc & 7);
        long bfr = *reinterpret_cast<const long*>(&Bs[buf][rloc * KB + pg * 16 + (q & 1) * 8]);
#pragma unroll
        for (int m = 0; m < 4; ++m)
          acc[m] = __builtin_amdgcn_mfma_f32_16x16x32_fp8_fp8(afr[m][s], bfr, acc[m], 0, 0, 0);
      }
      const int gcol = C0 + ns * 64 + nt * 16;
#pragma unroll
      for (int m = 0; m < 4; ++m) {
        if (gcol == rbase + m * 16) {   // wave-uniform diagonal tile
#pragma unroll
          for (int r = 0; r < 4; ++r) {
            float e = EXP2F(acc[m][r]);
            if (c15 == q * 4 + r) e = 0.f;  // sim[i][i]
            rowsum[m][r] += e;
          }
        } else {
#pragma unroll
          for (int r = 0; r < 4; ++r) rowsum[m][r] += EXP2F(acc[m][r]);
        }
      }
    }
  }

  // block combine: lane-reduce 16 cols -> per-wave partials in LDS -> sum the
  // 4 col-strips -> one plain store per (row, quarter), written exactly once.
  __syncthreads();
  float* red = (float*)BsRaw;   // 16 waves x 64 rows
#pragma unroll
  for (int m = 0; m < 4; ++m)
#pragma unroll
    for (int r = 0; r < 4; ++r) {
      float v = rowsum[m][r];
      v += __shfl_xor(v, 1);
      v += __shfl_xor(v, 2);
      v += __shfl_xor(v, 4);
      v += __shfl_xor(v, 8);
      if (c15 == 0) red[w * 64 + m * 16 + q * 4 + r] = v;
    }
  __syncthreads();
  if (t < BROW) {
    int g2 = t >> 6, rr = t & 63;
    float sv = red[(g2 * 4 + 0) * 64 + rr] + red[(g2 * 4 + 1) * 64 + rr] +
               red[(g2 * 4 + 2) * 64 + rr] + red[(g2 * 4 + 3) * 64 + rr];
    Spart[quarter * N2 + bt * BROW + g2 * 64 + rr] = sv;
  }
}

// ---------------- phase C: finalize ----------------------------------------
__device__ __forceinline__ void phaseC(const float* __restrict__ z,
                                       const float* __restrict__ Spart,
                                       float* __restrict__ out,
                                       int bid, int t, float* sred) {
  const int w = t >> 6, l = t & 63;
  const int wid = bid * 16 + w;       // 4096 waves, 4 rows each
  float wsum = 0.f;
#pragma unroll
  for (int rr = 0; rr < 4; ++rr) {
    int i  = wid * 4 + rr;
    int jj = i ^ NHALF;              // positive pair index
    const float2* zi = (const float2*)(z + (size_t)i * 128);
    const float2* zj = (const float2*)(z + (size_t)jj * 128);
    float2 a = zi[l], b2 = zj[l];
    float d = a.x * b2.x + a.y * b2.y;
    d += __shfl_xor(d, 1);
    d += __shfl_xor(d, 2);
    d += __shfl_xor(d, 4);
    d += __shfl_xor(d, 8);
    d += __shfl_xor(d, 16);
    d += __shfl_xor(d, 32);
    if (l == 0) {
      float Sv = Spart[i] + Spart[N2 + i] + Spart[2 * N2 + i] + Spart[3 * N2 + i];
      wsum += LOG2F(Sv) * 0.69314718055994531f - 2.f * d;
    }
  }
  if (l == 0) sred[w] = wsum;
  __syncthreads();
  if (t == 0) {
    float s = 0.f;
#pragma unroll
    for (int k = 0; k < 16; ++k) s += sred[k];
    atomicAdd(out, s * (1.f / N2));
  }
}

// ---------------- fused cooperative kernel (primary path) ------------------
// Grid 256 x block 1024: exactly 1 block/CU -> cooperative co-residency is
// trivially satisfiable (R6's grid=512/2-per-CU launch was rejected by the
// runtime and silently did nothing). 16 waves/CU = 4 waves/SIMD.
__global__ __launch_bounds__(1024, 4) void k_fused(const float* __restrict__ z,
                                                   unsigned char* __restrict__ zq,
                                                   float* __restrict__ Spart,
                                                   float* __restrict__ out) {
  __shared__ __align__(16) unsigned char Bs[2][BCOL * KB];  // 64 KiB
  cg::grid_group grid = cg::this_grid();
  phaseA(z, zq, out, blockIdx.x, threadIdx.x);
  grid.sync();
  phaseB(zq, Spart, blockIdx.x, threadIdx.x, &Bs[0][0]);
  grid.sync();
  phaseC(z, Spart, out, blockIdx.x, threadIdx.x, (float*)&Bs[0][0]);
}

// ---------------- fallback: same phases as 3 ordinary kernels --------------
__global__ __launch_bounds__(1024) void k_cv(const float* __restrict__ z,
                                             unsigned char* __restrict__ zq,
                                             float* __restrict__ out) {
  phaseA(z, zq, out, blockIdx.x, threadIdx.x);
}
__global__ __launch_bounds__(1024, 4) void k_gm(const unsigned char* __restrict__ zq,
                                                float* __restrict__ Spart) {
  __shared__ __align__(16) unsigned char Bs[2][BCOL * KB];
  phaseB(zq, Spart, blockIdx.x, threadIdx.x, &Bs[0][0]);
}
__global__ __launch_bounds__(1024) void k_fin(const float* __restrict__ z,
                                              const float* __restrict__ Spart,
                                              float* __restrict__ out) {
  __shared__ float sred[16];
  phaseC(z, Spart, out, blockIdx.x, threadIdx.x, sred);
}

extern "C" void kernel_launch(void* const* d_in, const int* in_sizes, int n_in,
                              void* d_out, int out_size, void* d_ws, size_t ws_size,
                              hipStream_t stream) {
  const float* z = (const float*)d_in[0];
  float* out = (float*)d_out;
  unsigned char* zq = (unsigned char*)d_ws;                       // 2 MB fp8 copy of z
  float* Spart = (float*)((char*)d_ws + (size_t)N2 * KB);         // 4 x 16384 floats

  void* args[] = {(void*)&z, (void*)&zq, (void*)&Spart, (void*)&out};
  hipError_t e = hipLaunchCooperativeKernel(reinterpret_cast<void*>(k_fused),
                                            dim3(256), dim3(1024), args, 0, stream);
  if (e != hipSuccess) {
    (void)hipGetLastError();   // clear sticky error; deterministic fallback
    k_cv<<<256, 1024, 0, stream>>>(z, zq, out);
    k_gm<<<256, 1024, 0, stream>>>(zq, Spart);
    k_fin<<<256, 1024, 0, stream>>>(z, Spart, out);
  }
}

// Round 8
// 191.796 us; speedup vs baseline: 1.0025x; 1.0025x over previous
//
#include <hip/hip_runtime.h>
#include <hip/hip_fp8.h>
#include <hip/hip_cooperative_groups.h>

namespace cg = cooperative_groups;

#define N2    16384
#define NHALF 8192
#define KB    128      // bytes per row in fp8
#define BROW  256      // rows per block (4 row-groups x 64)
#define BCOL  256      // B-tile cols per iteration (256*128B = 32 KB/tile)
#define NQUARTER 4096  // cols per block (grid = 64 row-tiles x 4 col-quarters)
#define NITER (NQUARTER / BCOL)   // 16

using f32x4 = __attribute__((ext_vector_type(4))) float;

// exp(2*dot) == exp2(dot * 2*log2(e)); fold sqrt(2*log2(e)) into z before fp8
// quantization so the MFMA result is already in exp2 domain.
#define PRESCALE 1.6986436005760381f   // sqrt(2*log2(e))

#if __has_builtin(__builtin_amdgcn_exp2f)
#define EXP2F(x) __builtin_amdgcn_exp2f(x)
#else
#define EXP2F(x) exp2f(x)
#endif
#if __has_builtin(__builtin_amdgcn_logf)
#define LOG2F(x) __builtin_amdgcn_logf(x)
#else
#define LOG2F(x) log2f(x)
#endif

typedef const __attribute__((address_space(1))) void* gas_ptr;
typedef __attribute__((address_space(3))) void* las_ptr;

// ---------------- phase A: f32 -> fp8 e4m3 (prescaled) + zero out ----------
__device__ __forceinline__ void phaseA(const float* __restrict__ z,
                                       unsigned char* __restrict__ zq,
                                       float* __restrict__ out, int bid, int t) {
  int g = bid * 1024 + t;               // 262144 threads x 8 elems
  const float4* zin = (const float4*)z;
  float4 v0 = zin[2 * g], v1 = zin[2 * g + 1];
#if __has_builtin(__builtin_amdgcn_cvt_pk_fp8_f32)
  int lo = __builtin_amdgcn_cvt_pk_fp8_f32(v0.x * PRESCALE, v0.y * PRESCALE, 0, 0);
  lo     = __builtin_amdgcn_cvt_pk_fp8_f32(v0.z * PRESCALE, v0.w * PRESCALE, lo, 1);
  int hi = __builtin_amdgcn_cvt_pk_fp8_f32(v1.x * PRESCALE, v1.y * PRESCALE, 0, 0);
  hi     = __builtin_amdgcn_cvt_pk_fp8_f32(v1.z * PRESCALE, v1.w * PRESCALE, hi, 1);
  ((int2*)zq)[g] = make_int2(lo, hi);
#else
  float f[8] = {v0.x, v0.y, v0.z, v0.w, v1.x, v1.y, v1.z, v1.w};
  unsigned long long pk = 0;
  for (int u = 0; u < 8; ++u) {
    __hip_fp8_e4m3 qv(f[u] * PRESCALE);
    pk |= ((unsigned long long)qv.__x) << (8 * u);
  }
  ((unsigned long long*)zq)[g] = pk;
#endif
  if (g == 0) out[0] = 0.f;
}

// ---------------- phase B: fused GEMM + exp2 + per-(row,quarter) sums ------
// bid decodes as (bt = bid>>2) x (quarter = bid&3); 16 waves = 4 row-groups x
// 4 col-strips(64). A fragments (fp8: 2 VGPRs per 16x16x32 operand -> 32
// VGPRs total) register-resident. B: double-buffered 32 KB LDS tiles via
// global_load_lds DMA; XOR granule swizzle (row,k8)->(row,k8^(row&7)) applied
// on source addresses (DMA LDS dest is lane-linear).
__device__ __forceinline__ void phaseB(const unsigned char* __restrict__ zq,
                                       float* __restrict__ Spart,
                                       int bid, int t, unsigned char* BsRaw) {
  unsigned char (*Bs)[BCOL * KB] = (unsigned char (*)[BCOL * KB])BsRaw;
  const int w = t >> 6, l = t & 63, q = l >> 4, c15 = l & 15;
  const int bt = bid >> 2, quarter = bid & 3;
  const int mg = w >> 2, ns = w & 3;
  const int rbase = bt * BROW + mg * 64;

  int srcoff[2];
#pragma unroll
  for (int j = 0; j < 2; ++j) {
    int p   = j * 1024 + t;      // physical granule id in tile (2048 x 16 B)
    int row = p >> 3;
    int pg  = p & 7;
    int k8  = pg ^ (row & 7);
    srcoff[j] = row * KB + k8 * 16;
  }

  const unsigned char* tile0 = zq + (size_t)(quarter * NQUARTER) * KB;
#pragma unroll
  for (int j = 0; j < 2; ++j)
    __builtin_amdgcn_global_load_lds((gas_ptr)(tile0 + srcoff[j]),
                                     (las_ptr)(&Bs[0][j * 16384 + w * 1024]), 16, 0, 0);

  // A fragments, fp8 16x16x32: lane holds A[m=lane&15][k=q*8+j] (8 bytes)
  long afr[4][4];
#pragma unroll
  for (int m = 0; m < 4; ++m) {
    const unsigned char* ap = zq + (size_t)(rbase + m * 16 + c15) * KB + q * 8;
#pragma unroll
    for (int s = 0; s < 4; ++s)
      afr[m][s] = *reinterpret_cast<const long*>(ap + s * 32);
  }

  float rowsum[4][4];
#pragma unroll
  for (int m = 0; m < 4; ++m)
#pragma unroll
    for (int r = 0; r < 4; ++r) rowsum[m][r] = 0.f;

  for (int it = 0; it < NITER; ++it) {
    const int buf = it & 1;
    const int C0  = quarter * NQUARTER + it * BCOL;
    __syncthreads();   // drains this wave's DMA (vmcnt) for tile it

    if (it + 1 < NITER) {
      const unsigned char* src = tile0 + (size_t)(it + 1) * BCOL * KB;
#pragma unroll
      for (int j = 0; j < 2; ++j)
        __builtin_amdgcn_global_load_lds((gas_ptr)(src + srcoff[j]),
                                         (las_ptr)(&Bs[buf ^ 1][j * 16384 + w * 1024]), 16, 0, 0);
    }

#pragma unroll
    for (int nt = 0; nt < 4; ++nt) {
      const int rloc = ns * 64 + nt * 16 + c15;   // B row within tile
      f32x4 acc[4];
#pragma unroll
      for (int m = 0; m < 4; ++m) acc[m] = (f32x4){0.f, 0.f, 0.f, 0.f};
#pragma unroll
      for (int s = 0; s < 4; ++s) {
        int pg = (2 * s + (q >> 1)) ^ (rloc & 7);
        long bfr = *reinterpret_cast<const long*>(&Bs[buf][rloc * KB + pg * 16 + (q & 1) * 8]);
#pragma unroll
        for (int m = 0; m < 4; ++m)
          acc[m] = __builtin_amdgcn_mfma_f32_16x16x32_fp8_fp8(afr[m][s], bfr, acc[m], 0, 0, 0);
      }
      const int gcol = C0 + ns * 64 + nt * 16;
#pragma unroll
      for (int m = 0; m < 4; ++m) {
        if (gcol == rbase + m * 16) {   // wave-uniform diagonal tile
#pragma unroll
          for (int r = 0; r < 4; ++r) {
            float e = EXP2F(acc[m][r]);
            if (c15 == q * 4 + r) e = 0.f;  // sim[i][i]
            rowsum[m][r] += e;
          }
        } else {
#pragma unroll
          for (int r = 0; r < 4; ++r) rowsum[m][r] += EXP2F(acc[m][r]);
        }
      }
    }
  }

  // block combine: lane-reduce 16 cols -> per-wave partials in LDS -> sum the
  // 4 col-strips -> one plain store per (row, quarter), written exactly once.
  __syncthreads();
  float* red = (float*)BsRaw;   // 16 waves x 64 rows
#pragma unroll
  for (int m = 0; m < 4; ++m)
#pragma unroll
    for (int r = 0; r < 4; ++r) {
      float v = rowsum[m][r];
      v += __shfl_xor(v, 1);
      v += __shfl_xor(v, 2);
      v += __shfl_xor(v, 4);
      v += __shfl_xor(v, 8);
      if (c15 == 0) red[w * 64 + m * 16 + q * 4 + r] = v;
    }
  __syncthreads();
  if (t < BROW) {
    int g2 = t >> 6, rr = t & 63;
    float sv = red[(g2 * 4 + 0) * 64 + rr] + red[(g2 * 4 + 1) * 64 + rr] +
               red[(g2 * 4 + 2) * 64 + rr] + red[(g2 * 4 + 3) * 64 + rr];
    Spart[quarter * N2 + bt * BROW + g2 * 64 + rr] = sv;
  }
}

// ---------------- phase C: finalize ----------------------------------------
__device__ __forceinline__ void phaseC(const float* __restrict__ z,
                                       const float* __restrict__ Spart,
                                       float* __restrict__ out,
                                       int bid, int t, float* sred) {
  const int w = t >> 6, l = t & 63;
  const int wid = bid * 16 + w;       // 4096 waves, 4 rows each
  float wsum = 0.f;
#pragma unroll
  for (int rr = 0; rr < 4; ++rr) {
    int i  = wid * 4 + rr;
    int jj = i ^ NHALF;              // positive pair index
    const float2* zi = (const float2*)(z + (size_t)i * 128);
    const float2* zj = (const float2*)(z + (size_t)jj * 128);
    float2 a = zi[l], b2 = zj[l];
    float d = a.x * b2.x + a.y * b2.y;
    d += __shfl_xor(d, 1);
    d += __shfl_xor(d, 2);
    d += __shfl_xor(d, 4);
    d += __shfl_xor(d, 8);
    d += __shfl_xor(d, 16);
    d += __shfl_xor(d, 32);
    if (l == 0) {
      float Sv = Spart[i] + Spart[N2 + i] + Spart[2 * N2 + i] + Spart[3 * N2 + i];
      wsum += LOG2F(Sv) * 0.69314718055994531f - 2.f * d;
    }
  }
  if (l == 0) sred[w] = wsum;
  __syncthreads();
  if (t == 0) {
    float s = 0.f;
#pragma unroll
    for (int k = 0; k < 16; ++k) s += sred[k];
    atomicAdd(out, s * (1.f / N2));
  }
}

// ---------------- fused cooperative kernel (primary path) ------------------
// Grid 256 x block 1024: exactly 1 block/CU (R7: launches fine).
// __launch_bounds__ 2nd arg behaves as min BLOCKS per CU (CUDA semantics),
// clamped to 32 waves/CU — R2/R5/R7 all show (.,4) -> VGPR cap 64 -> spill;
// R3 shows (512,2)=16 waves/CU -> cap 128, no spill. For a 1024-thread block
// the correct value for cap-128 is 1 (1 block = 16 waves/CU = 4 waves/EU).
__global__ __launch_bounds__(1024, 1) void k_fused(const float* __restrict__ z,
                                                   unsigned char* __restrict__ zq,
                                                   float* __restrict__ Spart,
                                                   float* __restrict__ out) {
  __shared__ __align__(16) unsigned char Bs[2][BCOL * KB];  // 64 KiB
  cg::grid_group grid = cg::this_grid();
  phaseA(z, zq, out, blockIdx.x, threadIdx.x);
  grid.sync();
  phaseB(zq, Spart, blockIdx.x, threadIdx.x, &Bs[0][0]);
  grid.sync();
  phaseC(z, Spart, out, blockIdx.x, threadIdx.x, (float*)&Bs[0][0]);
}

// ---------------- fallback: same phases as 3 ordinary kernels --------------
__global__ __launch_bounds__(1024, 1) void k_cv(const float* __restrict__ z,
                                                unsigned char* __restrict__ zq,
                                                float* __restrict__ out) {
  phaseA(z, zq, out, blockIdx.x, threadIdx.x);
}
__global__ __launch_bounds__(1024, 1) void k_gm(const unsigned char* __restrict__ zq,
                                                float* __restrict__ Spart) {
  __shared__ __align__(16) unsigned char Bs[2][BCOL * KB];
  phaseB(zq, Spart, blockIdx.x, threadIdx.x, &Bs[0][0]);
}
__global__ __launch_bounds__(1024, 1) void k_fin(const float* __restrict__ z,
                                                 const float* __restrict__ Spart,
                                                 float* __restrict__ out) {
  __shared__ float sred[16];
  phaseC(z, Spart, out, blockIdx.x, threadIdx.x, sred);
}

extern "C" void kernel_launch(void* const* d_in, const int* in_sizes, int n_in,
                              void* d_out, int out_size, void* d_ws, size_t ws_size,
                              hipStream_t stream) {
  const float* z = (const float*)d_in[0];
  float* out = (float*)d_out;
  unsigned char* zq = (unsigned char*)d_ws;                       // 2 MB fp8 copy of z
  float* Spart = (float*)((char*)d_ws + (size_t)N2 * KB);         // 4 x 16384 floats

  void* args[] = {(void*)&z, (void*)&zq, (void*)&Spart, (void*)&out};
  hipError_t e = hipLaunchCooperativeKernel(reinterpret_cast<void*>(k_fused),
                                            dim3(256), dim3(1024), args, 0, stream);
  if (e != hipSuccess) {
    (void)hipGetLastError();   // clear sticky error; deterministic fallback
    k_cv<<<256, 1024, 0, stream>>>(z, zq, out);
    k_gm<<<256, 1024, 0, stream>>>(zq, Spart);
    k_fin<<<256, 1024, 0, stream>>>(z, Spart, out);
  }
}